// Round 6
// baseline (247.761 us; speedup 1.0000x reference)
//
#include <hip/hip_runtime.h>

#define L_SEQ   4096
#define D_MODEL 512
#define NSEQ    2048   // BATCH * D_MODEL
#define CH      128    // chunk length
#define NC      32     // chunks

// workspace float offsets
#define OFF_P    0        // P = A^128, [i][j] row-major, 4096
#define OFF_W1T  4096     // W1T[r][i] = (A^{127-r} b)[i], 128x64
#define OFF_WOUT 12288    // Wout[i][r] = (c^T A^{r+1})[i], 64x128
#define OFF_KLOC 20480    // KlocZ[0..127]=0, KlocZ[128+m]=c^T A^m b, 256
#define OFF_GX   20736    // gx[c][i][s]: proj writes G^T, scan overwrites X^T

#define BC(v, j) __int_as_float(__builtin_amdgcn_readlane(__float_as_int(v), (j)))

// acc[8][4] += {a0,a1} (8 rows) * b (4 cols)
#define FMAC84(acc, a0, a1, b)                                                \
  acc[0][0]+=a0.x*b.x; acc[0][1]+=a0.x*b.y; acc[0][2]+=a0.x*b.z; acc[0][3]+=a0.x*b.w; \
  acc[1][0]+=a0.y*b.x; acc[1][1]+=a0.y*b.y; acc[1][2]+=a0.y*b.z; acc[1][3]+=a0.y*b.w; \
  acc[2][0]+=a0.z*b.x; acc[2][1]+=a0.z*b.y; acc[2][2]+=a0.z*b.z; acc[2][3]+=a0.z*b.w; \
  acc[3][0]+=a0.w*b.x; acc[3][1]+=a0.w*b.y; acc[3][2]+=a0.w*b.z; acc[3][3]+=a0.w*b.w; \
  acc[4][0]+=a1.x*b.x; acc[4][1]+=a1.x*b.y; acc[4][2]+=a1.x*b.z; acc[4][3]+=a1.x*b.w; \
  acc[5][0]+=a1.y*b.x; acc[5][1]+=a1.y*b.y; acc[5][2]+=a1.y*b.z; acc[5][3]+=a1.y*b.w; \
  acc[6][0]+=a1.z*b.x; acc[6][1]+=a1.z*b.y; acc[6][2]+=a1.z*b.z; acc[6][3]+=a1.z*b.w; \
  acc[7][0]+=a1.w*b.x; acc[7][1]+=a1.w*b.y; acc[7][2]+=a1.w*b.z; acc[7][3]+=a1.w*b.w;

// ===========================================================================
// k_prep (1 block): P=A^128 via 7 squarings (8x4 micro, all-b128 LDS reads
// via maintained transposes); four 64-step chains in 4 waves; emit P, W1T,
// Wout, KlocZ.
// ===========================================================================
__global__ __launch_bounds__(256) void k_prep(
    const float* __restrict__ A, const float* __restrict__ B,
    const float* __restrict__ C, float* __restrict__ ws) {
  __shared__ float M0[64][68], M0T[64][68], M1[64][68], M1T[64][68];
  __shared__ float Asv[64][68], AsvT[64][68];
  __shared__ float vrT[128][65];  // vrT[m][i] = (A^m b)[i]
  __shared__ float Cs[64], Bsh[64];

  const int tid = threadIdx.x;
  if (tid < 64) { Cs[tid] = C[tid]; Bsh[tid] = B[tid]; }
  for (int e = tid; e < 4096; e += 256) {
    const int i = e >> 6, j = e & 63;
    const float a = A[e];
    M0[i][j] = a; M0T[j][i] = a;
    Asv[i][j] = a; AsvT[j][i] = a;
  }
  __syncthreads();

  // ---- 7 squarings: it0 M1=A^2 ... it5 M0=A^64, it6 M1=A^128 ----
  const int rt = (tid >> 4) * 8;  // rows (tid<128): 0..56
  const int ct = (tid & 15) * 4;  // cols 0..60
  for (int it = 0; it < 7; ++it) {
    if (tid < 128) {
      float (*src)[68]  = (it & 1) ? M1 : M0;
      float (*srcT)[68] = (it & 1) ? M1T : M0T;
      float (*dst)[68]  = (it & 1) ? M0 : M1;
      float (*dstT)[68] = (it & 1) ? M0T : M1T;
      float acc[8][4] = {{0.f}};
#pragma unroll 8
      for (int k = 0; k < 64; ++k) {
        const float4 a0 = *(const float4*)&srcT[k][rt];      // src rows rt..rt+3, col k
        const float4 a1 = *(const float4*)&srcT[k][rt + 4];
        const float4 b  = *(const float4*)&src[k][ct];
        FMAC84(acc, a0, a1, b);
      }
#pragma unroll
      for (int j = 0; j < 8; ++j) {
        float4 v; v.x = acc[j][0]; v.y = acc[j][1]; v.z = acc[j][2]; v.w = acc[j][3];
        *(float4*)&dst[rt + j][ct] = v;
      }
#pragma unroll
      for (int cc = 0; cc < 4; ++cc) {
        float4 v0, v1;
        v0.x = acc[0][cc]; v0.y = acc[1][cc]; v0.z = acc[2][cc]; v0.w = acc[3][cc];
        v1.x = acc[4][cc]; v1.y = acc[5][cc]; v1.z = acc[6][cc]; v1.w = acc[7][cc];
        *(float4*)&dstT[ct + cc][rt] = v0;
        *(float4*)&dstT[ct + cc][rt + 4] = v1;
      }
    }
    __syncthreads();
  }

  // ---- chains (4 waves): vr m0..63 | vr m64..127 | cw m1..64 | cw m65..128
  const int lane = tid & 63, wv = tid >> 6;
  float* Wg = ws + OFF_WOUT;
  {
    float reg[64];
    if (wv == 0) {
#pragma unroll
      for (int j4 = 0; j4 < 16; ++j4) {
        const float4 v = *(const float4*)&Asv[lane][j4 * 4];
        reg[j4*4] = v.x; reg[j4*4+1] = v.y; reg[j4*4+2] = v.z; reg[j4*4+3] = v.w;
      }
      float cur = Bsh[lane];
      vrT[0][lane] = cur;
      for (int m = 1; m < 64; ++m) {
        float nv = 0.f;
#pragma unroll
        for (int j = 0; j < 64; ++j) nv += reg[j] * BC(cur, j);
        cur = nv;
        vrT[m][lane] = cur;
      }
    } else if (wv == 1) {
#pragma unroll
      for (int j4 = 0; j4 < 16; ++j4) {
        const float4 v = *(const float4*)&Asv[lane][j4 * 4];
        reg[j4*4] = v.x; reg[j4*4+1] = v.y; reg[j4*4+2] = v.z; reg[j4*4+3] = v.w;
      }
      const float b0 = Bsh[lane];
      float cur = 0.f;
#pragma unroll
      for (int j4 = 0; j4 < 16; ++j4) {   // cur = (A^64 b)[lane] via M0 rows
        const float4 v = *(const float4*)&M0[lane][j4 * 4];
        cur += v.x * BC(b0, j4*4) + v.y * BC(b0, j4*4+1) +
               v.z * BC(b0, j4*4+2) + v.w * BC(b0, j4*4+3);
      }
      vrT[64][lane] = cur;
      for (int m = 65; m < 128; ++m) {
        float nv = 0.f;
#pragma unroll
        for (int j = 0; j < 64; ++j) nv += reg[j] * BC(cur, j);
        cur = nv;
        vrT[m][lane] = cur;
      }
    } else if (wv == 2) {
#pragma unroll
      for (int j4 = 0; j4 < 16; ++j4) {   // columns of A
        const float4 v = *(const float4*)&AsvT[lane][j4 * 4];
        reg[j4*4] = v.x; reg[j4*4+1] = v.y; reg[j4*4+2] = v.z; reg[j4*4+3] = v.w;
      }
      float cur = Cs[lane];
      for (int m = 1; m <= 64; ++m) {
        float nv = 0.f;
#pragma unroll
        for (int j = 0; j < 64; ++j) nv += reg[j] * BC(cur, j);
        cur = nv;
        Wg[lane * 128 + m - 1] = cur;
      }
    } else {
#pragma unroll
      for (int j4 = 0; j4 < 16; ++j4) {
        const float4 v = *(const float4*)&AsvT[lane][j4 * 4];
        reg[j4*4] = v.x; reg[j4*4+1] = v.y; reg[j4*4+2] = v.z; reg[j4*4+3] = v.w;
      }
      const float c0 = Cs[lane];
      float cur = 0.f;
#pragma unroll
      for (int j4 = 0; j4 < 16; ++j4) {   // cur = (c^T A^64)[lane] via M0T rows
        const float4 v = *(const float4*)&M0T[lane][j4 * 4];
        cur += v.x * BC(c0, j4*4) + v.y * BC(c0, j4*4+1) +
               v.z * BC(c0, j4*4+2) + v.w * BC(c0, j4*4+3);
      }
      for (int m = 65; m <= 128; ++m) {
        float nv = 0.f;
#pragma unroll
        for (int j = 0; j < 64; ++j) nv += reg[j] * BC(cur, j);
        cur = nv;
        Wg[lane * 128 + m - 1] = cur;
      }
    }
  }
  __syncthreads();

  // W1T[r][i] = vr[127-r][i]
  float* W1Tg = ws + OFF_W1T;
  for (int e = tid; e < 8192; e += 256) {
    const int r = e >> 6, i = e & 63;
    W1Tg[e] = vrT[127 - r][i];
  }
  // KlocZ
  float* Kz = ws + OFF_KLOC;
  if (tid < 128) {
    float acc = 0.f;
#pragma unroll
    for (int i = 0; i < 64; ++i) acc += Cs[i] * vrT[tid][i];
    Kz[128 + tid] = acc;
  } else {
    Kz[tid - 128] = 0.f;
  }
  // P
  float* Pg = ws + OFF_P;
  for (int e = tid; e < 4096; e += 256) Pg[e] = M1[e >> 6][e & 63];
}

// ===========================================================================
// k_proj: G^T[c][i][s] = sum_r W1T[r][i] * u[c*128+r][s]
// 64 i x 64 s per block, K=128 (two staged halves). A-operand read directly
// from the L1-resident W1T table (2 VMEM b128/kk); LDS serves only the u tile
// (1 b128/kk, 2-way). 128 threads, micro 8x4.
// ===========================================================================
__global__ __launch_bounds__(128) void k_proj(
    const float* __restrict__ u, const float* __restrict__ wsr,
    float* __restrict__ gx) {
  __shared__ float Us[64][64];   // exact stride: flat/contiguous staging

  const int st = blockIdx.x;     // 0..31 (64 seqs)
  const int c  = blockIdx.y;     // 0..31
  const int tid = threadIdx.x;
  const int s0 = st * 64;
  const int bi = s0 >> 9, d0 = s0 & 511;
  const float* W1Tg = wsr + OFF_W1T;
  const float* ub = u + ((size_t)bi * L_SEQ + c * CH) * D_MODEL + d0;
  const int ig = tid >> 4;       // i rows ig*8..+7
  const int sg = tid & 15;       // s cols sg*4..+3

  float acc[8][4] = {{0.f}};
  for (int h = 0; h < 2; ++h) {
    __syncthreads();
#pragma unroll
    for (int n = 0; n < 8; ++n) {
      const int e = tid + 128 * n;              // 1024 float4, flat
      const int rr = e >> 4, s4 = (e & 15) * 4;
      *(((float4*)Us) + e) =
          *(const float4*)(ub + (size_t)(h * 64 + rr) * D_MODEL + s4);
    }
    __syncthreads();
#pragma unroll 4
    for (int rr = 0; rr < 64; ++rr) {
      const float* wr = W1Tg + (size_t)(h * 64 + rr) * 64 + ig * 8;
      const float4 a0 = *(const float4*)wr;
      const float4 a1 = *(const float4*)(wr + 4);
      const float4 b  = *(const float4*)&Us[rr][sg * 4];
      FMAC84(acc, a0, a1, b);
    }
  }

  float* gb = gx + (size_t)c * 64 * NSEQ + s0 + sg * 4;
#pragma unroll
  for (int j = 0; j < 8; ++j) {
    float4 v; v.x = acc[j][0]; v.y = acc[j][1]; v.z = acc[j][2]; v.w = acc[j][3];
    *(float4*)(gb + (size_t)(ig * 8 + j) * NSEQ) = v;
  }
}

// ===========================================================================
// k_scan: x_{c+1} = P x_c + g_c; overwrites g[c] region (layout [c][i][s])
// with pre-chunk state X^T[c][i][s] (same layout -> block-disjoint in s ->
// race-free in place). 1024 threads / 16 waves per block; wave = one seq.
// g reads and X^T writes are 64B-granule cooperative via LDS.
// ===========================================================================
__global__ __launch_bounds__(1024) void k_scan(
    const float* __restrict__ wsr, float* __restrict__ gx) {
  __shared__ float gbuf[2][64][17];
  __shared__ float xbuf[64][17];
  const int tid = threadIdx.x;
  const int lane = tid & 63, wv = tid >> 6;   // wv 0..15
  const int s0 = blockIdx.x * 16;
  const int ci = tid >> 4, cj = tid & 15;     // coop: row i, s-offset

  float p[64];
#pragma unroll
  for (int j4 = 0; j4 < 16; ++j4) {
    const float4 v = *(const float4*)(wsr + OFF_P + lane * 64 + j4 * 4);
    p[j4*4] = v.x; p[j4*4+1] = v.y; p[j4*4+2] = v.z; p[j4*4+3] = v.w;
  }

  gbuf[0][ci][cj] = gx[(size_t)ci * NSEQ + s0 + cj];
  __syncthreads();

  float x = 0.f;
  for (int c = 0; c < NC; ++c) {
    const int buf = c & 1;
    if (c + 1 < NC)
      gbuf[buf ^ 1][ci][cj] = gx[(size_t)((c + 1) * 64 + ci) * NSEQ + s0 + cj];
    xbuf[lane][wv] = x;
    __syncthreads();
    gx[(size_t)(c * 64 + ci) * NSEQ + s0 + cj] = xbuf[ci][cj];  // X^T[c]
    const float g = gbuf[buf][lane][wv];
    float x0 = g, x1 = 0.f;
#pragma unroll
    for (int j = 0; j < 64; j += 2) {
      x0 += p[j] * BC(x, j);
      x1 += p[j + 1] * BC(x, j + 1);
    }
    x = x0 + x1;
    __syncthreads();
  }
}

// ===========================================================================
// k_localout: y[c*128+r][s] = sum_{k<=r} Kloc[r-k] u[c*128+k][s]
//                           + sum_i Wout[i][r] X_c[i][s]
// 128 rows x 64 seqs per block, 256 threads, micro 8x4. A-operands come
// straight from L1-resident KlocZ (unaligned 16B) / Wout tables; LDS holds
// only the 64x64 B tile (exact stride, contiguous staging, 2-way reads).
// ===========================================================================
__global__ __launch_bounds__(256) void k_localout(
    const float* __restrict__ u, const float* __restrict__ wsr,
    const float* __restrict__ gx, float* __restrict__ out) {
  __shared__ float Bs[64][64];

  const int st = blockIdx.x;    // 0..31 (64 seqs)
  const int c  = blockIdx.y;    // 0..31
  const int tid = threadIdx.x;
  const int s0 = st * 64;
  const int bi = s0 >> 9, d0 = s0 & 511;
  const int rg = tid >> 4;      // rows rg*8..+7 (0..120)
  const int sq = tid & 15;      // cols sq*4..+3
  const float* KlocZ = wsr + OFF_KLOC;
  const float* WoutG = wsr + OFF_WOUT;
  const float* ub = u + ((size_t)bi * L_SEQ + c * CH) * D_MODEL + d0;

  float acc[8][4] = {{0.f}};

  // ---- A1: k rows 0..63, all output rows ----
#pragma unroll
  for (int n = 0; n < 4; ++n) {
    const int e = tid + 256 * n;
    *(((float4*)Bs) + e) =
        *(const float4*)(ub + (size_t)(e >> 4) * D_MODEL + (e & 15) * 4);
  }
  __syncthreads();
  {
    const float* k0p = KlocZ + 128 + rg * 8;
#pragma unroll 4
    for (int kk = 0; kk < 64; ++kk) {
      float4 a0, a1;
      __builtin_memcpy(&a0, k0p - kk, 16);
      __builtin_memcpy(&a1, k0p - kk + 4, 16);
      const float4 b = *(const float4*)&Bs[kk][sq * 4];
      FMAC84(acc, a0, a1, b);
    }
  }
  __syncthreads();

  // ---- A2: k rows 64..127, only output rows >= 64 (waves 2,3) ----
#pragma unroll
  for (int n = 0; n < 4; ++n) {
    const int e = tid + 256 * n;
    *(((float4*)Bs) + e) =
        *(const float4*)(ub + (size_t)(64 + (e >> 4)) * D_MODEL + (e & 15) * 4);
  }
  __syncthreads();
  if (rg >= 8) {
    const float* k0p = KlocZ + 64 + rg * 8;
#pragma unroll 4
    for (int kk = 0; kk < 64; ++kk) {
      float4 a0, a1;
      __builtin_memcpy(&a0, k0p - kk, 16);
      __builtin_memcpy(&a1, k0p - kk + 4, 16);
      const float4 b = *(const float4*)&Bs[kk][sq * 4];
      FMAC84(acc, a0, a1, b);
    }
  }
  __syncthreads();

  // ---- B: Wout * X_c (X^T[c][i][s] from gx) ----
#pragma unroll
  for (int n = 0; n < 4; ++n) {
    const int e = tid + 256 * n;
    *(((float4*)Bs) + e) = *(const float4*)(
        gx + (size_t)(c * 64 + (e >> 4)) * NSEQ + s0 + (e & 15) * 4);
  }
  __syncthreads();
  {
#pragma unroll 4
    for (int kk = 0; kk < 64; ++kk) {
      const float* wp = WoutG + kk * 128 + rg * 8;
      const float4 a0 = *(const float4*)wp;
      const float4 a1 = *(const float4*)(wp + 4);
      const float4 b = *(const float4*)&Bs[kk][sq * 4];
      FMAC84(acc, a0, a1, b);
    }
  }

  // ---- epilogue ----
  float* ob = out + ((size_t)bi * L_SEQ + c * CH) * D_MODEL + d0 + sq * 4;
#pragma unroll
  for (int j = 0; j < 8; ++j) {
    float4 v; v.x = acc[j][0]; v.y = acc[j][1]; v.z = acc[j][2]; v.w = acc[j][3];
    *(float4*)(ob + (size_t)(rg * 8 + j) * D_MODEL) = v;
  }
}

extern "C" void kernel_launch(void* const* d_in, const int* in_sizes, int n_in,
                              void* d_out, int out_size, void* d_ws,
                              size_t ws_size, hipStream_t stream) {
  const float* u = (const float*)d_in[0];   // (4, 4096, 512)
  const float* A = (const float*)d_in[1];   // (64, 64)
  const float* B = (const float*)d_in[2];   // (64, 1)
  const float* C = (const float*)d_in[3];   // (1, 64)
  float* out = (float*)d_out;
  float* ws = (float*)d_ws;                 // needs ~16.9 MB
  float* gx = ws + OFF_GX;

  k_prep<<<1, 256, 0, stream>>>(A, B, C, ws);
  k_proj<<<dim3(32, 32), 128, 0, stream>>>(u, ws, gx);
  k_scan<<<128, 1024, 0, stream>>>(ws, gx);
  k_localout<<<dim3(32, 32), 256, 0, stream>>>(u, ws, gx, out);
}